// Round 18
// baseline (452.642 us; speedup 1.0000x reference)
//
#include <hip/hip_runtime.h>
#include <math.h>

#define N_NODES 20000
#define E_EDGES 320000
#define IN_CH   300
#define HID     100
#define R_REL   50
#define NB      8
#define CLS     3
#define NQ      64
#define OUTW    800   // NB * HID
#define ZW      128   // Z row stride (ushorts): 256-B rows, batched-4 writes
#define KP1     320
#define KP2     128
#define SCAN_BLKS ((N_NODES + 255) / 256)   // 79

typedef unsigned short ushort_t;
typedef __attribute__((ext_vector_type(8))) short     short8;
typedef __attribute__((ext_vector_type(8))) unsigned short ushort8;
typedef __attribute__((ext_vector_type(4))) float     f32x4;
typedef __attribute__((ext_vector_type(2))) float     f32x2;

__device__ __forceinline__ ushort_t f2bf_rne(float f) {   // round-nearest-even
    unsigned u = __float_as_uint(f);
    unsigned r = (u + 0x7fffu + ((u >> 16) & 1u)) >> 16;
    return (ushort_t)r;
}
__device__ __forceinline__ float bf2f(ushort_t u) {
    return __uint_as_float((unsigned)u << 16);
}

// ============================ CSR build =================================
__global__ __launch_bounds__(256) void zero_deg2(int* __restrict__ dd,
                                                 int* __restrict__ ds) {
    int i = blockIdx.x * 256 + threadIdx.x;
    if (i < N_NODES) { dd[i] = 0; ds[i] = 0; }
}

__global__ __launch_bounds__(256) void hist2_kernel(
        const int* __restrict__ ei, int* __restrict__ dd,
        int* __restrict__ ds) {
    int e = blockIdx.x * 256 + threadIdx.x;
    if (e < E_EDGES) {
        atomicAdd(&dd[ei[E_EDGES + e]], 1);
        atomicAdd(&ds[ei[e]], 1);
    }
}

// dual-set scans: blockIdx selects (deg_d...) or (deg_s...) set
__global__ __launch_bounds__(256) void scan1_both(
        const int* __restrict__ deg_d, int* __restrict__ rp_d, int* __restrict__ bsum_d,
        const int* __restrict__ deg_s, int* __restrict__ rp_s, int* __restrict__ bsum_s) {
    int set = blockIdx.x / SCAN_BLKS, blk = blockIdx.x % SCAN_BLKS;
    const int* deg = set ? deg_s : deg_d;
    int* rowptr    = set ? rp_s  : rp_d;
    int* bsum      = set ? bsum_s : bsum_d;
    __shared__ int s[256];
    int tid = threadIdx.x;
    int idx = blk * 256 + tid;
    int v = (idx < N_NODES) ? deg[idx] : 0;
    s[tid] = v; __syncthreads();
    #pragma unroll
    for (int off = 1; off < 256; off <<= 1) {
        int t = (tid >= off) ? s[tid - off] : 0;
        __syncthreads();
        s[tid] += t;
        __syncthreads();
    }
    if (idx < N_NODES) rowptr[idx] = s[tid] - v;   // exclusive
    if (tid == 255) bsum[blk] = s[255];
}

__global__ __launch_bounds__(128) void scan2_both(
        int* __restrict__ bsum_d, int* __restrict__ rp_d,
        int* __restrict__ bsum_s, int* __restrict__ rp_s) {
    int* bsum   = blockIdx.x ? bsum_s : bsum_d;
    int* rowptr = blockIdx.x ? rp_s   : rp_d;
    __shared__ int s[128];
    int tid = threadIdx.x;
    int v = (tid < SCAN_BLKS) ? bsum[tid] : 0;
    s[tid] = v; __syncthreads();
    #pragma unroll
    for (int off = 1; off < 128; off <<= 1) {
        int t = (tid >= off) ? s[tid - off] : 0;
        __syncthreads();
        s[tid] += t;
        __syncthreads();
    }
    if (tid < SCAN_BLKS) bsum[tid] = s[tid] - v;   // exclusive
    if (tid == 0) rowptr[N_NODES] = E_EDGES;
}

__global__ __launch_bounds__(256) void scan3_both(
        int* __restrict__ rp_d, const int* __restrict__ bsum_d, int* __restrict__ cur_d,
        int* __restrict__ rp_s, const int* __restrict__ bsum_s, int* __restrict__ cur_s) {
    int set = blockIdx.x / SCAN_BLKS, blk = blockIdx.x % SCAN_BLKS;
    int* rowptr      = set ? rp_s   : rp_d;
    const int* bsum  = set ? bsum_s : bsum_d;
    int* cursor      = set ? cur_s  : cur_d;
    int idx = blk * 256 + threadIdx.x;
    if (idx < N_NODES) {
        int v = rowptr[idx] + bsum[blk];
        rowptr[idx] = v;
        cursor[idx] = v;
    }
}

// fused scatter: dst-CSR key (src,rel), src-CSR key (rel), and zidx map
__global__ __launch_bounds__(256) void scatter_both(
        const int* __restrict__ ei, const int* __restrict__ et,
        int* __restrict__ cur_d, int* __restrict__ cur_s,
        int* __restrict__ skey, int* __restrict__ skey_s,
        int* __restrict__ zidx) {
    int e = blockIdx.x * 256 + threadIdx.x;
    if (e >= E_EDGES) return;
    int s = ei[e], d = ei[E_EDGES + e], rt = et[e];
    int p = atomicAdd(&cur_d[d], 1);
    skey[p] = (s << 6) | rt;                 // dst-order: (src, rel)
    int qp = atomicAdd(&cur_s[s], 1);
    skey_s[qp] = rt;                         // src-order: rel only
    zidx[p] = qp;                            // dst-slot -> Z row (src-slot)
}

// ---- both layers' basis -> Bt (transposed bf16, zero-padded), one dispatch ----
__global__ __launch_bounds__(256) void split_bt_both(
        const float* __restrict__ basis1, ushort_t* __restrict__ Bt1,
        const float* __restrict__ basis2, ushort_t* __restrict__ Bt2) {
    int idx = blockIdx.x * 256 + threadIdx.x;
    const int n1 = OUTW * KP1;
    if (idx < n1) {
        int n = idx / KP1, k = idx - n * KP1;
        int b = n / HID, o = n - b * HID;
        float v = (k < IN_CH) ? basis1[((size_t)b * IN_CH + k) * HID + o] : 0.f;
        Bt1[idx] = f2bf_rne(v);
    } else {
        int i2 = idx - n1;
        if (i2 >= OUTW * KP2) return;
        int n = i2 / KP2, k = i2 - n * KP2;
        int b = n / HID, o = n - b * HID;
        float v = (k < HID) ? basis2[((size_t)b * HID + k) * HID + o] : 0.f;
        Bt2[i2] = f2bf_rne(v);
    }
}

// ---- x fp32 [N,300] -> Ab1 bf16 [N,320] zero-padded ----
__global__ __launch_bounds__(256) void convert_x(
        const float* __restrict__ x, ushort_t* __restrict__ Ab) {
    int idx = blockIdx.x * 256 + threadIdx.x;
    if (idx >= N_NODES * KP1) return;
    int m = idx / KP1, k = idx - m * KP1;
    float v = (k < IN_CH) ? x[(size_t)m * IN_CH + k] : 0.f;
    Ab[idx] = f2bf_rne(v);
}

// ---- MFMA GEMM, no LDS, no barriers: xbh = Ab(bf16) * Bt(bf16) ----
// Fragments loaded straight global->VGPR (per-row 64B segments, L1/L2-hot);
// waves fully independent. Grid (625 row-blocks, 5 col-blocks), 4 waves.
#define BM 32
#define BN 160
__global__ __launch_bounds__(256) void gemm_nolds(
        const ushort_t* __restrict__ Ab, const ushort_t* __restrict__ Bt,
        ushort_t* __restrict__ xbh, int Kp) {
    int tid  = threadIdx.x;
    int lane = tid & 63, wave = tid >> 6;
    int ml = lane & 15, quad = lane >> 4;
    int wr = (wave >> 1) * 16, wc = (wave & 1) * 80;
    int row0 = blockIdx.x * BM;          // 20000 % 32 == 0: no bounds checks
    int col0 = blockIdx.y * BN;
    int ksteps = Kp >> 5;

    const ushort_t* ap = Ab + (size_t)(row0 + wr + ml) * Kp + quad * 8;
    const ushort_t* bp0 = Bt + (size_t)(col0 + wc + ml) * Kp + quad * 8;
    size_t bstride16 = (size_t)16 * Kp;  // 16 rows ahead

    f32x4 acc[5] = {};
    #pragma unroll 2
    for (int ks = 0; ks < ksteps; ks++) {
        int ko = ks << 5;
        short8 af = *(const short8*)(ap + ko);
        #pragma unroll
        for (int nt = 0; nt < 5; nt++) {
            short8 bfv = *(const short8*)(bp0 + nt * bstride16 + ko);
            acc[nt] = __builtin_amdgcn_mfma_f32_16x16x32_bf16(af, bfv, acc[nt], 0, 0, 0);
        }
    }
    #pragma unroll
    for (int nt = 0; nt < 5; nt++) {
        #pragma unroll
        for (int r = 0; r < 4; r++) {
            int grow = row0 + wr + quad * 4 + r;
            xbh[(size_t)grow * OUTW + col0 + wc + nt * 16 + ml] =
                f2bf_rne(acc[nt][r]);
        }
    }
}

// ---- xbq[n,b] = xbh[n,b,:].q ; xbk likewise (reads bf16 xbh, coalesced) ----
__global__ __launch_bounds__(256) void qk3_kernel(
        const ushort_t* __restrict__ xbh, const float* __restrict__ q,
        const float* __restrict__ k, float* __restrict__ xbq,
        float* __restrict__ xbk) {
    __shared__ float sq[HID], sk[HID];
    int tid = threadIdx.x;
    if (tid < HID) { sq[tid] = q[tid]; sk[tid] = k[tid]; }
    __syncthreads();
    int idx = blockIdx.x * 256 + tid;     // idx = n*8 + b
    if (idx >= N_NODES * NB) return;
    const ushort_t* xr = xbh + (size_t)(idx >> 3) * OUTW + (idx & 7) * HID;
    float aq = 0.f, ak = 0.f;
    #pragma unroll
    for (int c = 0; c < 25; c++) {        // 25 x ushort4 (8B aligned)
        ushort4 v = *(const ushort4*)&xr[c * 4];
        #pragma unroll
        for (int i = 0; i < 4; i++) {
            float f = bf2f(((const ushort_t*)&v)[i]);
            aq = fmaf(f, sq[c * 4 + i], aq);
            ak = fmaf(f, sk[c * 4 + i], ak);
        }
    }
    xbq[idx] = aq;
    xbk[idx] = ak;
}

// ==== src-major, batched-4 Z rows; comp in LDS; keys via register window ====
__global__ __launch_bounds__(256) void compute_z(
        const int* __restrict__ rowptr_s, const int* __restrict__ skey_s,
        const float* __restrict__ comp, const ushort_t* __restrict__ xbh,
        ushort_t* __restrict__ Z) {
    __shared__ float scomp[R_REL * NB];   // 1.6 KB
    int tid = threadIdx.x;
    for (int i = tid; i < R_REL * NB; i += 256) scomp[i] = comp[i];
    __syncthreads();
    int wave = tid >> 6, lane = tid & 63;
    int s = blockIdx.x * 4 + wave;
    if (s >= N_NODES) return;
    int beg = rowptr_s[s], end = rowptr_s[s + 1];
    if (beg == end) return;
    int eg = lane >> 4, c16 = lane & 15;
    int cbase = c16 * 8;
    float xr[NB][8];
    #pragma unroll
    for (int b = 0; b < NB; b++)
        #pragma unroll
        for (int i = 0; i < 8; i++) xr[b][i] = 0.f;
    if (cbase < HID) {
        #pragma unroll
        for (int b = 0; b < NB; b++) {
            const ushort_t* base = xbh + (size_t)s * OUTW + b * HID + cbase;
            ushort4 v0 = *(const ushort4*)base;       // 8B aligned
            xr[b][0] = bf2f(v0.x); xr[b][1] = bf2f(v0.y);
            xr[b][2] = bf2f(v0.z); xr[b][3] = bf2f(v0.w);
            if (cbase + 8 <= HID) {
                ushort4 v1 = *(const ushort4*)(base + 4);
                xr[b][4] = bf2f(v1.x); xr[b][5] = bf2f(v1.y);
                xr[b][6] = bf2f(v1.z); xr[b][7] = bf2f(v1.w);
            }
        }
    }
    for (int w0 = beg; w0 < end; w0 += 64) {
        int kw = (w0 + lane < end) ? skey_s[w0 + lane] : 0;
        int wend = w0 + 64 < end ? w0 + 64 : end;
        for (int p0 = w0; p0 < wend; p0 += 4) {
            int j = p0 - w0 + eg;              // < 64 always
            int rt = __shfl(kw, j) & 63;       // zero memory ops in chain
            int p = p0 + eg;
            const float* cr = &scomp[rt * NB];
            float z[8] = {};
            #pragma unroll
            for (int b = 0; b < NB; b++) {
                float cb = cr[b];
                #pragma unroll
                for (int i = 0; i < 8; i++) z[i] = fmaf(cb, xr[b][i], z[i]);
            }
            ushort8 zz;
            #pragma unroll
            for (int i = 0; i < 8; i++) zz[i] = f2bf_rne(z[i]);
            if (p < end)
                *(ushort8*)&Z[(size_t)p * ZW + cbase] = zz;   // 16B, coalesced
        }
    }
}

// ==== dst-major: online softmax + paired-edge Z gather + bias ====
// mode 0: write fp32 h. mode 1: write relu(h) as bf16, KP2-padded (layer-2 A).
__global__ __launch_bounds__(256) void msg_soft(
        const int* __restrict__ rowptr, const int* __restrict__ skey,
        const int* __restrict__ zidx,
        const float* __restrict__ comp, const ushort_t* __restrict__ Z,
        const float* __restrict__ xbq, const float* __restrict__ xbk,
        const float* __restrict__ bias, float* __restrict__ h,
        ushort_t* __restrict__ hb, int mode) {
    __shared__ float scomp[R_REL * NB];   // 1.6 KB
    int tid = threadIdx.x;
    for (int i = tid; i < R_REL * NB; i += 256) scomp[i] = comp[i];
    __syncthreads();
    int wave = tid >> 6, lane = tid & 63;
    int d = blockIdx.x * 4 + wave;
    if (d >= N_NODES) return;
    int beg = rowptr[d], end = rowptr[d + 1];

    float4 qd0 = *(const float4*)&xbq[d * NB];
    float4 qd1 = *(const float4*)&xbq[d * NB + 4];

    int l5 = lane & 31;
    bool act = l5 < 25;
    int oc = l5 * 4;                  // channel base (4 channels per lane)
    f32x4 acc = {0.f, 0.f, 0.f, 0.f};
    float m = -1e30f, l = 0.f;

    for (int c0 = beg; c0 < end; c0 += 64) {
        int p = c0 + lane;
        bool valid = p < end;
        float a = -1e30f;
        int zi = 0;
        if (valid) {
            int key = skey[p];
            zi = zidx[p];
            int s = key >> 6, rt = key & 63;
            const float4 c0v = *(const float4*)&scomp[rt * NB];
            const float4 c1v = *(const float4*)&scomp[rt * NB + 4];
            const float4 k0v = *(const float4*)&xbk[s * NB];
            const float4 k1v = *(const float4*)&xbk[s * NB + 4];
            float qi = c0v.x*qd0.x + c0v.y*qd0.y + c0v.z*qd0.z + c0v.w*qd0.w
                     + c1v.x*qd1.x + c1v.y*qd1.y + c1v.z*qd1.z + c1v.w*qd1.w;
            float kj = c0v.x*k0v.x + c0v.y*k0v.y + c0v.z*k0v.z + c0v.w*k0v.w
                     + c1v.x*k1v.x + c1v.y*k1v.y + c1v.z*k1v.z + c1v.w*k1v.w;
            a = qi + kj;
            a = a > 0.f ? a : 0.2f * a;     // leaky_relu 0.2
        }
        float cm = a;
        #pragma unroll
        for (int off = 32; off; off >>= 1) cm = fmaxf(cm, __shfl_xor(cm, off));
        float M = fmaxf(m, cm);
        float scale = __expf(m - M);
        acc *= scale; l *= scale; m = M;
        float wgt = valid ? __expf(a - M) : 0.f;
        float cs = wgt;
        #pragma unroll
        for (int off = 32; off; off >>= 1) cs += __shfl_xor(cs, off);
        l += cs;
        int cnt = end - c0; if (cnt > 64) cnt = 64;
        for (int j = 0; j < cnt; j += 2) {
            int jj = j + (lane >> 5);         // even half: j, odd half: j+1
            float wj = __shfl(wgt, jj);       // invalid -> 0
            int   zj = __shfl(zi, jj);
            if (act) {
                ushort4 zz = *(const ushort4*)&Z[(size_t)zj * ZW + oc];
                acc.x = fmaf(wj, bf2f(zz.x), acc.x);
                acc.y = fmaf(wj, bf2f(zz.y), acc.y);
                acc.z = fmaf(wj, bf2f(zz.z), acc.z);
                acc.w = fmaf(wj, bf2f(zz.w), acc.w);
            }
        }
    }
    // combine even/odd-edge halves: lane ℓ (<25) += lane ℓ+32
    #pragma unroll
    for (int i = 0; i < 4; i++) acc[i] += __shfl_xor(acc[i], 32);
    if (mode == 0) {
        if (lane < 25) {
            float inv = 1.f / (l + 1e-16f);
            float4 r;
            r.x = bias[oc]     + acc.x * inv;
            r.y = bias[oc + 1] + acc.y * inv;
            r.z = bias[oc + 2] + acc.z * inv;
            r.w = bias[oc + 3] + acc.w * inv;
            *(float4*)&h[(size_t)d * HID + oc] = r;   // 16B aligned (400|16)
        }
    } else {
        if (lane < 25) {
            float inv = 1.f / (l + 1e-16f);
            ushort4 r;
            r.x = f2bf_rne(fmaxf(bias[oc]     + acc.x * inv, 0.f));
            r.y = f2bf_rne(fmaxf(bias[oc + 1] + acc.y * inv, 0.f));
            r.z = f2bf_rne(fmaxf(bias[oc + 2] + acc.z * inv, 0.f));
            r.w = f2bf_rne(fmaxf(bias[oc + 3] + acc.w * inv, 0.f));
            *(ushort4*)&hb[(size_t)d * KP2 + oc] = r;
        } else if (lane < 32) {
            ushort4 zz4 = {0, 0, 0, 0};       // pad channels 100..127
            *(ushort4*)&hb[(size_t)d * KP2 + oc] = zz4;
        }
    }
}

// ---- pooled = mean(relu(h2[qidx])); out = pooled @ Wl^T + bl ----
__global__ __launch_bounds__(128) void head_kernel(
        const float* __restrict__ h2, const int* __restrict__ qidx,
        const float* __restrict__ Wl, const float* __restrict__ bl,
        float* __restrict__ out) {
    __shared__ float pooled[HID];
    int tid = threadIdx.x;
    if (tid < HID) {
        float s = 0.f;
        for (int i = 0; i < NQ; i++)
            s += fmaxf(h2[(size_t)qidx[i] * HID + tid], 0.f);
        pooled[tid] = s * (1.0f / NQ);
    }
    __syncthreads();
    if (tid < CLS) {
        float s = bl[tid];
        for (int o = 0; o < HID; o++) s = fmaf(pooled[o], Wl[tid * HID + o], s);
        out[tid] = s;
    }
}

extern "C" void kernel_launch(void* const* d_in, const int* in_sizes, int n_in,
                              void* d_out, int out_size, void* d_ws, size_t ws_size,
                              hipStream_t stream) {
    const float* x      = (const float*)d_in[0];
    const int*   ei     = (const int*)  d_in[1];
    const int*   et     = (const int*)  d_in[2];
    const int*   qidx   = (const int*)  d_in[3];
    const float* comp1  = (const float*)d_in[4];
    const float* basis1 = (const float*)d_in[5];
    const float* q1     = (const float*)d_in[6];
    const float* k1     = (const float*)d_in[7];
    const float* b1     = (const float*)d_in[8];
    const float* comp2  = (const float*)d_in[9];
    const float* basis2 = (const float*)d_in[10];
    const float* q2     = (const float*)d_in[11];
    const float* k2     = (const float*)d_in[12];
    const float* b2     = (const float*)d_in[13];
    const float* Wl     = (const float*)d_in[14];
    const float* bl     = (const float*)d_in[15];
    float* out = (float*)d_out;

    char* w = (char*)d_ws;
    size_t off = 0;
    auto alloc = [&](size_t nbytes) {
        void* p = (void*)(w + off);
        off += ((nbytes + 255) / 256) * 256;
        return p;
    };
    ushort_t* xbh    = (ushort_t*)alloc((size_t)N_NODES * OUTW * 2); // 32 MB
    ushort_t* Z      = (ushort_t*)alloc((size_t)E_EDGES * ZW * 2);   // 82 MB
    ushort_t* Ab1    = (ushort_t*)alloc((size_t)N_NODES * KP1 * 2);  // 12.8 MB
    ushort_t* Ab2    = (ushort_t*)alloc((size_t)N_NODES * KP2 * 2);  // 5.1 MB
    float*    h2     = (float*)alloc((size_t)N_NODES * HID * 4);     // 8 MB
    ushort_t* Bt1    = (ushort_t*)alloc((size_t)OUTW * KP1 * 2);     // 512 KB
    ushort_t* Bt2    = (ushort_t*)alloc((size_t)OUTW * KP2 * 2);     // 205 KB
    float*    xbq    = (float*)alloc((size_t)N_NODES * NB * 4);
    float*    xbk    = (float*)alloc((size_t)N_NODES * NB * 4);
    int*      deg_d  = (int*)alloc(N_NODES * 4);
    int*      deg_s  = (int*)alloc(N_NODES * 4);
    int*      rp_d   = (int*)alloc((N_NODES + 1) * 4);
    int*      rp_s   = (int*)alloc((N_NODES + 1) * 4);
    int*      cur_d  = (int*)alloc(N_NODES * 4);
    int*      cur_s  = (int*)alloc(N_NODES * 4);
    int*      bsum_d = (int*)alloc(SCAN_BLKS * 4);
    int*      bsum_s = (int*)alloc(SCAN_BLKS * 4);
    int*      skey   = (int*)alloc(E_EDGES * 4);
    int*      skey_s = (int*)alloc(E_EDGES * 4);
    int*      zidx   = (int*)alloc(E_EDGES * 4);

    // ---- CSR build + Bt + Ab1 upfront ----
    zero_deg2<<<SCAN_BLKS, 256, 0, stream>>>(deg_d, deg_s);
    hist2_kernel<<<(E_EDGES + 255) / 256, 256, 0, stream>>>(ei, deg_d, deg_s);
    scan1_both<<<2 * SCAN_BLKS, 256, 0, stream>>>(deg_d, rp_d, bsum_d, deg_s, rp_s, bsum_s);
    scan2_both<<<2, 128, 0, stream>>>(bsum_d, rp_d, bsum_s, rp_s);
    scan3_both<<<2 * SCAN_BLKS, 256, 0, stream>>>(rp_d, bsum_d, cur_d, rp_s, bsum_s, cur_s);
    scatter_both<<<(E_EDGES + 255) / 256, 256, 0, stream>>>(ei, et, cur_d, cur_s, skey, skey_s, zidx);
    split_bt_both<<<(OUTW * (KP1 + KP2) + 255) / 256, 256, 0, stream>>>(basis1, Bt1, basis2, Bt2);
    convert_x<<<(N_NODES * KP1 + 255) / 256, 256, 0, stream>>>(x, Ab1);

    dim3 gg(N_NODES / BM, OUTW / BN);   // (625, 5)

    // ---- layer 1 (msg_soft writes relu'd bf16 Ab2 for layer 2) ----
    gemm_nolds<<<gg, 256, 0, stream>>>(Ab1, Bt1, xbh, KP1);
    qk3_kernel<<<(N_NODES * NB + 255) / 256, 256, 0, stream>>>(xbh, q1, k1, xbq, xbk);
    compute_z<<<(N_NODES + 3) / 4, 256, 0, stream>>>(rp_s, skey_s, comp1, xbh, Z);
    msg_soft<<<(N_NODES + 3) / 4, 256, 0, stream>>>(rp_d, skey, zidx, comp1, Z, xbq, xbk, b1, nullptr, Ab2, 1);

    // ---- layer 2 ----
    gemm_nolds<<<gg, 256, 0, stream>>>(Ab2, Bt2, xbh, KP2);
    qk3_kernel<<<(N_NODES * NB + 255) / 256, 256, 0, stream>>>(xbh, q2, k2, xbq, xbk);
    compute_z<<<(N_NODES + 3) / 4, 256, 0, stream>>>(rp_s, skey_s, comp2, xbh, Z);
    msg_soft<<<(N_NODES + 3) / 4, 256, 0, stream>>>(rp_d, skey, zidx, comp2, Z, xbq, xbk, b2, h2, nullptr, 0);

    head_kernel<<<1, 128, 0, stream>>>(h2, qidx, Wl, bl, out);
}